// Round 7
// baseline (1059.785 us; speedup 1.0000x reference)
//
#include <hip/hip_runtime.h>
#include <hip/hip_fp16.h>
#include <stdint.h>

typedef __attribute__((ext_vector_type(8)))  _Float16 f16x8;
typedef __attribute__((ext_vector_type(4)))  _Float16 f16x4;
typedef __attribute__((ext_vector_type(4)))  float    f32x4;
typedef __attribute__((ext_vector_type(16))) float    f32x16;

__device__ __forceinline__ void split4(const f32x4 v, f16x4 &h, f16x4 &l) {
    #pragma unroll
    for (int i = 0; i < 4; ++i) {
        float a = v[i];
        _Float16 hh = (_Float16)a;        // v_cvt_f16_f32 (RNE)
        h[i] = hh;
        l[i] = (_Float16)(a - (float)hh); // residual, rel err ~2^-24
    }
}

// ================= pre-split: f32 [rows x 4096] -> f16 hi/lo planes =================
__global__ __launch_bounds__(256)
void split_rows(const float* __restrict__ src, _Float16* __restrict__ h,
                _Float16* __restrict__ l, int srcRows, long long total4)
{
    const long long stride = (long long)gridDim.x * blockDim.x;
    for (long long i = (long long)blockIdx.x * blockDim.x + threadIdx.x; i < total4; i += stride) {
        const long long e = i << 2;
        const int row = (int)(e >> 12);      // cols = 4096
        f16x4 hv = {}, lv = {};
        if (row < srcRows) {
            f32x4 v = *(const f32x4*)(src + e);
            split4(v, hv, lv);
        }
        *(f16x4*)(h + e) = hv;
        *(f16x4*)(l + e) = lv;
    }
}

// ================= split-3 GEMM on 32x32x16 MFMA, single-sync K-step =================
// C[m][n] = act( sum_k A[m][k]*B[n][k] + bias[n] ), A/B as f16 hi/lo planes.
// BM = MI*32, BN = 256, BK = 32, 8 waves (2M x 4N). One barrier + vmcnt(0) per
// K-step; all staging issued at step top (full-step slack >> HBM latency, so the
// drain is free). Within the step, ds_reads and MFMAs are compiler/HW-interleaved.
// Bank-conflict-free chunk map: read position (lhi*2+kh)^kxor (lanes l and l+32
// differ in chunk bit 1 -> bank groups 8 apart under either DS lane-phasing).

#define BARRIER() __builtin_amdgcn_s_barrier()
#define SB0()     __builtin_amdgcn_sched_barrier(0)
#define MFMA32    __builtin_amdgcn_mfma_f32_32x32x16_f16

template<int N> __device__ __forceinline__ void VMCNT() {
    asm volatile("s_waitcnt vmcnt(%0)" :: "n"(N) : "memory");
    __builtin_amdgcn_sched_barrier(0);
}

__device__ __forceinline__ void gload16(const _Float16* g, _Float16* l) {
    __builtin_amdgcn_global_load_lds(
        (const __attribute__((address_space(1))) void*)g,
        (__attribute__((address_space(3))) void*)l, 16, 0, 0);
}

template<int MI, bool SPLITOUT, bool CHUNKSWZ>
__global__ __launch_bounds__(512, 2)
void gemm3_v7(const _Float16* __restrict__ Agh, const _Float16* __restrict__ Agl,
              const _Float16* __restrict__ Bgh, const _Float16* __restrict__ Bgl,
              const float* __restrict__ bias,
              _Float16* __restrict__ Oh, _Float16* __restrict__ Ol,
              float* __restrict__ Of, int ldo, int Nstore,
              int K, int nBN)
{
    extern __shared__ _Float16 lds[];
    constexpr int WROWS = MI * 16;           // per-wave m rows
    constexpr int BM    = MI * 32;
    constexpr int MB    = MI / 2;            // 32-row m-blocks per wave
    constexpr int CHA   = MI * 2;            // 1KB chunks per A plane
    constexpr int PW    = (2*CHA + 32) / 8;  // chunks per wave (8 or 6)
    constexpr int H1    = PW - CHA/8;        // slot-map helper (A-high tail)
    constexpr int H2    = CHA / 8;
    constexpr int ALO   = CHA * 512;
    constexpr int BHO   = 2 * CHA * 512;
    constexpr int BUFS  = 2*CHA*512 + 16384;

    const int tid  = threadIdx.x;
    const int lane = tid & 63;
    const int wave = tid >> 6;
    const int wm  = wave >> 2;
    const int wn  = wave & 3;
    const int l31 = lane & 31;
    const int lhi = lane >> 5;

    // ---- block swizzle ----
    int bm, bn;
    const int orig = blockIdx.x;
    if (CHUNKSWZ) {
        // GEMM1: 512 blocks = 32bm x 16bn; XCD k owns bm in [4k,4k+4), bn sweeping.
        bm = ((orig & 7) << 2) | ((orig >> 3) & 3);
        bn = orig >> 5;
    } else {
        // bn-inner: each XCD sweeps all bn for a contiguous bm range (A L2-resident)
        const int cpx  = gridDim.x >> 3;
        const int swzb = (orig & 7) * cpx + (orig >> 3);
        bn = swzb % nBN;
        bm = swzb / nBN;
    }
    const int m0 = bm * BM;
    const int n0 = bn * 256;

    // ---- staging descriptors (slot order arbitrary under single-sync) ----
    const _Float16* gptr[8];
    int loff[8];
    #pragma unroll
    for (int i = 0; i < PW; ++i) {
        int p, q;
        if (i < H2 || i >= H1) {
            const bool hi = (i >= H1);
            const int  s  = hi ? (i - H1) : i;
            const int  j  = wave * H2 + s;
            p = j / (CHA / 2);                    // 0=Ah, 1=Al
            const int v   = j % (CHA / 2);
            const int wmq = v / (MI / 2);
            const int wi  = v % (MI / 2);
            q = wmq * MI + (hi ? MI / 2 : 0) + wi;
        } else {
            q = (i - H2) + (wave & 3) * 4;
            p = 2 + (wave >> 2);
        }
        const int row = q*16 + (lane >> 2);
        const int gc  = (lane & 3) ^ ((row >> 1) & 3);
        const _Float16* plane = (p == 0) ? Agh : (p == 1) ? Agl : (p == 2) ? Bgh : Bgl;
        const size_t grow = (size_t)((p < 2) ? m0 : n0) + row;
        gptr[i] = plane + grow * (size_t)K + gc * 8;
        loff[i] = ((p < 2) ? p * ALO : BHO + (p - 2) * 8192) + q * 512;
    }

    // ---- fragment ds_read offsets (conflict-free chunk map) ----
    const int kxor = (l31 >> 1) & 3;
    int aoff[MB][2], boff[2][2];
    #pragma unroll
    for (int mb = 0; mb < MB; ++mb)
        #pragma unroll
        for (int kh = 0; kh < 2; ++kh)
            aoff[mb][kh] = (wm*WROWS + mb*32 + l31)*32 + ((lhi*2 + kh) ^ kxor)*8;
    #pragma unroll
    for (int nb2 = 0; nb2 < 2; ++nb2)
        #pragma unroll
        for (int kh = 0; kh < 2; ++kh)
            boff[nb2][kh] = BHO + (wn*64 + nb2*32 + l31)*32 + ((lhi*2 + kh) ^ kxor)*8;

    f32x16 acc[MB][2] = {};

    // prologue: stage tile 0
    #pragma unroll
    for (int i = 0; i < PW; ++i) { gload16(gptr[i], &lds[loff[i]]); gptr[i] += 32; }
    VMCNT<0>(); BARRIER(); SB0();

    const int NT = K >> 5;
    int bb = 0;
    for (int t = 0; t < NT; ++t) {
        const int nbuf = BUFS - bb;
        // issue next-tile staging FIRST (pinned above compute by SB0)
        if (t < NT - 1) {
            #pragma unroll
            for (int i = 0; i < PW; ++i) { gload16(gptr[i], &lds[nbuf + loff[i]]); gptr[i] += 32; }
        }
        SB0();
        // B-frags into registers (read once per step)
        f16x8 bh[2][2], bl[2][2];
        #pragma unroll
        for (int nb2 = 0; nb2 < 2; ++nb2)
            #pragma unroll
            for (int kh = 0; kh < 2; ++kh) {
                bh[nb2][kh] = *(const f16x8*)&lds[bb + boff[nb2][kh]];
                bl[nb2][kh] = *(const f16x8*)&lds[bb + 8192 + boff[nb2][kh]];
            }
        // compute: A-frags JIT; compiler interleaves ds_read/MFMA freely
        #pragma unroll
        for (int kh = 0; kh < 2; ++kh) {
            #pragma unroll
            for (int mb = 0; mb < MB; ++mb) {
                const f16x8 ah = *(const f16x8*)&lds[bb + aoff[mb][kh]];
                const f16x8 al = *(const f16x8*)&lds[bb + ALO + aoff[mb][kh]];
                #pragma unroll
                for (int n2 = 0; n2 < 2; ++n2) {
                    acc[mb][n2] = MFMA32(ah, bh[n2][kh], acc[mb][n2], 0, 0, 0);
                    acc[mb][n2] = MFMA32(ah, bl[n2][kh], acc[mb][n2], 0, 0, 0);
                    acc[mb][n2] = MFMA32(al, bh[n2][kh], acc[mb][n2], 0, 0, 0);
                }
            }
        }
        // single sync point: staging was issued a full step ago -> drain is cheap
        VMCNT<0>(); BARRIER(); SB0();
        bb = nbuf;
    }

    // ---- epilogue ----
    // 32x32 D mapping (HW-verified): col = lane&31, row = (r&3) + 8*(r>>2) + 4*(lane>>5)
    #pragma unroll
    for (int nb2 = 0; nb2 < 2; ++nb2) {
        const int n = n0 + wn*64 + nb2*32 + l31;
        if (!SPLITOUT && n >= Nstore) continue;
        const float bv = bias[n];
        #pragma unroll
        for (int mb = 0; mb < MB; ++mb) {
            #pragma unroll
            for (int r = 0; r < 16; ++r) {
                const int m = m0 + wm*WROWS + mb*32 + (r & 3) + 8*(r >> 2) + 4*lhi;
                float v = acc[mb][nb2][r] + bv;
                if (SPLITOUT) {
                    v = fmaxf(v, 0.f);
                    const _Float16 hh = (_Float16)v;
                    Oh[(size_t)m * ldo + n] = hh;
                    Ol[(size_t)m * ldo + n] = (_Float16)(v - (float)hh);
                } else {
                    Of[(size_t)m * ldo + n] = v;
                }
            }
        }
    }
}

// ================= fallback path (R2, known-passing) =================
#define TILE_M 128
#define TILE_N 128
#define TILE_K 32
#define LDSK   40

template<bool RELU, bool NGUARD>
__global__ __launch_bounds__(256, 2)
void gemm_split3(const float* __restrict__ A, const float* __restrict__ B,
                 const float* __restrict__ bias, float* __restrict__ C,
                 int K, int ldc, int Nreal)
{
    __shared__ _Float16 Ah[TILE_M][LDSK];
    __shared__ _Float16 Al[TILE_M][LDSK];
    __shared__ _Float16 Bh[TILE_N][LDSK];
    __shared__ _Float16 Bl[TILE_N][LDSK];

    const int tid  = threadIdx.x;
    const int lane = tid & 63;
    const int wave = tid >> 6;
    const int wr   = wave >> 1;
    const int wc   = wave & 1;
    const int m0   = blockIdx.x * TILE_M;
    const int n0   = blockIdx.y * TILE_N;
    const int srow = tid >> 3;
    const int scol = (tid & 7) << 2;
    const int fr = lane & 15;
    const int fg = lane >> 4;

    f32x4 acc[4][4] = {};

    for (int kt = 0; kt < K; kt += TILE_K) {
        __syncthreads();
        #pragma unroll
        for (int p = 0; p < 4; ++p) {
            const int row = srow + p * 32;
            f32x4 v = *(const f32x4*)(A + (size_t)(m0 + row) * K + kt + scol);
            f16x4 hv, lv;
            split4(v, hv, lv);
            *(f16x4*)&Ah[row][scol] = hv;
            *(f16x4*)&Al[row][scol] = lv;
        }
        #pragma unroll
        for (int p = 0; p < 4; ++p) {
            const int row = srow + p * 32;
            f32x4 v = {0.f, 0.f, 0.f, 0.f};
            if (!NGUARD || (n0 + row) < Nreal)
                v = *(const f32x4*)(B + (size_t)(n0 + row) * K + kt + scol);
            f16x4 hv, lv;
            split4(v, hv, lv);
            *(f16x4*)&Bh[row][scol] = hv;
            *(f16x4*)&Bl[row][scol] = lv;
        }
        __syncthreads();

        f16x8 ah[4], al[4];
        #pragma unroll
        for (int mi = 0; mi < 4; ++mi) {
            const int r = wr * 64 + mi * 16 + fr;
            ah[mi] = *(const f16x8*)&Ah[r][fg * 8];
            al[mi] = *(const f16x8*)&Al[r][fg * 8];
        }
        #pragma unroll
        for (int ni = 0; ni < 4; ++ni) {
            const int r = wc * 64 + ni * 16 + fr;
            const f16x8 bh = *(const f16x8*)&Bh[r][fg * 8];
            const f16x8 bl = *(const f16x8*)&Bl[r][fg * 8];
            #pragma unroll
            for (int mi = 0; mi < 4; ++mi) {
                acc[mi][ni] = __builtin_amdgcn_mfma_f32_16x16x32_f16(ah[mi], bh, acc[mi][ni], 0, 0, 0);
                acc[mi][ni] = __builtin_amdgcn_mfma_f32_16x16x32_f16(ah[mi], bl, acc[mi][ni], 0, 0, 0);
                acc[mi][ni] = __builtin_amdgcn_mfma_f32_16x16x32_f16(al[mi], bh, acc[mi][ni], 0, 0, 0);
            }
        }
    }

    #pragma unroll
    for (int ni = 0; ni < 4; ++ni) {
        const int n = n0 + wc * 64 + ni * 16 + fr;
        if (NGUARD && n >= Nreal) continue;
        const float bv = bias[n];
        #pragma unroll
        for (int mi = 0; mi < 4; ++mi) {
            #pragma unroll
            for (int j = 0; j < 4; ++j) {
                const int m = m0 + wr * 64 + mi * 16 + fg * 4 + j;
                float val = acc[mi][ni][j] + bv;
                if (RELU) val = fmaxf(val, 0.f);
                C[(size_t)m * ldc + n] = val;
            }
        }
    }
}

// In-place row softmax: one wave per row (cols <= 1024).
__global__ __launch_bounds__(256)
void softmax_rows(float* __restrict__ out, int rows, int cols)
{
    const int lane = threadIdx.x & 63;
    const int row  = blockIdx.x * 4 + (threadIdx.x >> 6);
    if (row >= rows) return;
    float* p = out + (size_t)row * cols;

    float v[16];
    float mx = -3.4e38f;
    #pragma unroll
    for (int j = 0; j < 16; ++j) {
        const int c = lane + j * 64;
        v[j] = (c < cols) ? p[c] : -3.4e38f;
        mx = fmaxf(mx, v[j]);
    }
    #pragma unroll
    for (int off = 32; off > 0; off >>= 1)
        mx = fmaxf(mx, __shfl_xor(mx, off));

    float s = 0.f;
    #pragma unroll
    for (int j = 0; j < 16; ++j) {
        const int c = lane + j * 64;
        const float e = (c < cols) ? __expf(v[j] - mx) : 0.f;
        v[j] = e;
        s += e;
    }
    #pragma unroll
    for (int off = 32; off > 0; off >>= 1)
        s += __shfl_xor(s, off);

    const float inv = 1.f / s;
    #pragma unroll
    for (int j = 0; j < 16; ++j) {
        const int c = lane + j * 64;
        if (c < cols) p[c] = v[j] * inv;
    }
}

// ================= host =================
extern "C" void kernel_launch(void* const* d_in, const int* in_sizes, int n_in,
                              void* d_out, int out_size, void* d_ws, size_t ws_size,
                              hipStream_t stream)
{
    const float* x  = (const float*)d_in[0];   // [8192, 4096]
    const float* w1 = (const float*)d_in[1];   // [4096, 4096]
    const float* b1 = (const float*)d_in[2];   // [4096]
    const float* w2 = (const float*)d_in[3];   // [1000, 4096]
    const float* b2 = (const float*)d_in[4];   // [1000]
    float* out = (float*)d_out;                // [8192, 1000] fp32

    const size_t SZ_X  = (size_t)8192 * 4096 * 2;
    const size_t SZ_W1 = (size_t)4096 * 4096 * 2;
    const size_t SZ_W2 = (size_t)1024 * 4096 * 2;

    size_t off = 0;
    auto take = [&](size_t b) { size_t o = off; off += (b + 255) & ~(size_t)255; return o; };
    const size_t o_xh  = take(SZ_X),  o_xl  = take(SZ_X);
    const size_t o_w1h = take(SZ_W1), o_w1l = take(SZ_W1);
    const size_t o_w2h = take(SZ_W2), o_w2l = take(SZ_W2);
    const size_t o_ah  = take(SZ_X),  o_al  = take(SZ_X);
    const size_t need = off;

    bool attr_ok =
        (hipFuncSetAttribute((const void*)gemm3_v7<8, true, true>,
                             hipFuncAttributeMaxDynamicSharedMemorySize, 131072) == hipSuccess) &&
        (hipFuncSetAttribute((const void*)gemm3_v7<4, false, false>,
                             hipFuncAttributeMaxDynamicSharedMemorySize, 131072) == hipSuccess);

    const dim3 blk256(256, 1, 1), blk512(512, 1, 1);

    if (attr_ok && ws_size >= need) {
        char* w = (char*)d_ws;
        _Float16 *xh  = (_Float16*)(w + o_xh),  *xl  = (_Float16*)(w + o_xl);
        _Float16 *w1h = (_Float16*)(w + o_w1h), *w1l = (_Float16*)(w + o_w1l);
        _Float16 *w2h = (_Float16*)(w + o_w2h), *w2l = (_Float16*)(w + o_w2l);
        _Float16 *ath = (_Float16*)(w + o_ah),  *atl = (_Float16*)(w + o_al);

        hipLaunchKernelGGL(split_rows, dim3(2048), blk256, 0, stream, x,  xh,  xl,  8192, (long long)8192 * 1024);
        hipLaunchKernelGGL(split_rows, dim3(2048), blk256, 0, stream, w1, w1h, w1l, 4096, (long long)4096 * 1024);
        hipLaunchKernelGGL(split_rows, dim3(1024), blk256, 0, stream, w2, w2h, w2l, 1000, (long long)1024 * 1024);

        // GEMM1: act(hi/lo) = relu(x @ w1^T + b1)   M=8192 N=4096 K=4096, BM=256, chunked swizzle
        hipLaunchKernelGGL((gemm3_v7<8, true, true>), dim3(512), blk512, 131072, stream,
                           xh, xl, w1h, w1l, b1, ath, atl, (float*)nullptr, 4096, 4096, 4096, 16);
        // GEMM2: logits = act @ w2^T + b2           M=8192 N=1024(pad) K=4096, BM=128, bn-inner
        hipLaunchKernelGGL((gemm3_v7<4, false, false>), dim3(256), blk512, 98304, stream,
                           ath, atl, w2h, w2l, b2, (_Float16*)nullptr, (_Float16*)nullptr,
                           out, 1000, 1000, 4096, 4);
        hipLaunchKernelGGL(softmax_rows, dim3(2048), blk256, 0, stream, out, 8192, 1000);
    } else {
        float* act = (float*)d_ws;
        hipLaunchKernelGGL((gemm_split3<true, false>), dim3(64, 32), blk256, 0, stream,
                           x, w1, b1, act, 4096, 4096, 4096);
        hipLaunchKernelGGL((gemm_split3<false, true>), dim3(64, 8), blk256, 0, stream,
                           act, w2, b2, out, 4096, 1000, 1000);
        hipLaunchKernelGGL(softmax_rows, dim3(2048), blk256, 0, stream, out, 8192, 1000);
    }
}

// Round 8
// 943.737 us; speedup vs baseline: 1.1230x; 1.1230x over previous
//
#include <hip/hip_runtime.h>
#include <hip/hip_fp16.h>
#include <stdint.h>

typedef __attribute__((ext_vector_type(8)))  _Float16 f16x8;
typedef __attribute__((ext_vector_type(4)))  _Float16 f16x4;
typedef __attribute__((ext_vector_type(4)))  float    f32x4;

__device__ __forceinline__ void split4(const f32x4 v, f16x4 &h, f16x4 &l) {
    #pragma unroll
    for (int i = 0; i < 4; ++i) {
        float a = v[i];
        _Float16 hh = (_Float16)a;        // v_cvt_f16_f32 (RNE)
        h[i] = hh;
        l[i] = (_Float16)(a - (float)hh); // residual, rel err ~2^-24
    }
}

// ================= pre-split: f32 [rows x 4096] -> f16 hi/lo planes =================
__global__ __launch_bounds__(256)
void split_rows(const float* __restrict__ src, _Float16* __restrict__ h,
                _Float16* __restrict__ l, int srcRows, long long total4)
{
    const long long stride = (long long)gridDim.x * blockDim.x;
    for (long long i = (long long)blockIdx.x * blockDim.x + threadIdx.x; i < total4; i += stride) {
        const long long e = i << 2;
        const int row = (int)(e >> 12);      // cols = 4096
        f16x4 hv = {}, lv = {};
        if (row < srcRows) {
            f32x4 v = *(const f32x4*)(src + e);
            split4(v, hv, lv);
        }
        *(f16x4*)(h + e) = hv;
        *(f16x4*)(l + e) = lv;
    }
}

// ================= split-3 GEMM, 16x16x32 core, SGB-interleaved single-sync =================
// C[m][n] = act( sum_k A[m][k]*B[n][k] + bias[n] ), A/B as f16 hi/lo planes.
// BM = MI*32, BN = 256, BK = 32, 8 waves (2M x 4N), dbuf LDS, 1 barrier/step.
// Read pattern = R3/R5-proven zero-conflict 16x16 pattern. B-frags in regs.
// sched_group_barrier pins per-step emission: [VMEM staging][DS B+A0][{DS 2, MFMA 12} x MI]
// so mi+1's ds_reads issue under mi's MFMAs (LDS pipe hides under MFMA pipe).

#define BARRIER() __builtin_amdgcn_s_barrier()
#define SB0()     __builtin_amdgcn_sched_barrier(0)
#define MFMA16    __builtin_amdgcn_mfma_f32_16x16x32_f16
#define SGB       __builtin_amdgcn_sched_group_barrier

template<int N> __device__ __forceinline__ void VMCNT() {
    asm volatile("s_waitcnt vmcnt(%0)" :: "n"(N) : "memory");
    __builtin_amdgcn_sched_barrier(0);
}

__device__ __forceinline__ void gload16(const _Float16* g, _Float16* l) {
    __builtin_amdgcn_global_load_lds(
        (const __attribute__((address_space(1))) void*)g,
        (__attribute__((address_space(3))) void*)l, 16, 0, 0);
}

template<int MI, bool SPLITOUT, bool CHUNKSWZ>
__global__ __launch_bounds__(512, 2)
void gemm3_v8(const _Float16* __restrict__ Agh, const _Float16* __restrict__ Agl,
              const _Float16* __restrict__ Bgh, const _Float16* __restrict__ Bgl,
              const float* __restrict__ bias,
              _Float16* __restrict__ Oh, _Float16* __restrict__ Ol,
              float* __restrict__ Of, int ldo, int Nstore,
              int K, int nBN)
{
    extern __shared__ _Float16 lds[];
    constexpr int WROWS = MI * 16;
    constexpr int BM    = MI * 32;
    constexpr int CHA   = MI * 2;            // 1KB chunks per A plane
    constexpr int PW    = (2*CHA + 32) / 8;  // chunks per wave (8 or 6)
    constexpr int H1    = PW - CHA/8;
    constexpr int H2    = CHA / 8;
    constexpr int ALO   = CHA * 512;
    constexpr int BHO   = 2 * CHA * 512;
    constexpr int BUFS  = 2*CHA*512 + 16384;

    const int tid  = threadIdx.x;
    const int lane = tid & 63;
    const int wave = tid >> 6;
    const int wm = wave >> 2;
    const int wn = wave & 3;
    const int fr = lane & 15;
    const int fg = lane >> 4;

    // ---- block swizzle ----
    int bm, bn;
    const int orig = blockIdx.x;
    if (CHUNKSWZ) {
        // GEMM1: 512 blocks = 32bm x 16bn; XCD k owns bm in [4k,4k+4), bn sweeping.
        bm = ((orig & 7) << 2) | ((orig >> 3) & 3);
        bn = orig >> 5;
    } else {
        // bn-inner: each XCD sweeps all bn for a contiguous bm range (A L2-resident)
        const int cpx  = gridDim.x >> 3;
        const int swzb = (orig & 7) * cpx + (orig >> 3);
        bn = swzb % nBN;
        bm = swzb / nBN;
    }
    const int m0 = bm * BM;
    const int n0 = bn * 256;

    // ---- staging descriptors (R5-proven; writes conflict-free) ----
    const _Float16* gptr[8];
    int loff[8];
    #pragma unroll
    for (int i = 0; i < PW; ++i) {
        int p, q;
        if (i < H2 || i >= H1) {
            const bool hi = (i >= H1);
            const int  s  = hi ? (i - H1) : i;
            const int  j  = wave * H2 + s;
            p = j / (CHA / 2);                    // 0=Ah, 1=Al
            const int v   = j % (CHA / 2);
            const int wmq = v / (MI / 2);
            const int wi  = v % (MI / 2);
            q = wmq * MI + (hi ? MI / 2 : 0) + wi;
        } else {
            q = (i - H2) + (wave & 3) * 4;
            p = 2 + (wave >> 2);
        }
        const int row = q*16 + (lane >> 2);
        const int gc  = (lane & 3) ^ ((row >> 1) & 3);
        const _Float16* plane = (p == 0) ? Agh : (p == 1) ? Agl : (p == 2) ? Bgh : Bgl;
        const size_t grow = (size_t)((p < 2) ? m0 : n0) + row;
        gptr[i] = plane + grow * (size_t)K + gc * 8;
        loff[i] = ((p < 2) ? p * ALO : BHO + (p - 2) * 8192) + q * 512;
    }

    // ---- fragment ds_read offsets: R3/R5-proven ZERO-conflict pattern ----
    const int swz8 = (fg ^ ((fr >> 1) & 3)) * 8;
    int aoff[MI], boff[4];
    #pragma unroll
    for (int mi = 0; mi < MI; ++mi) aoff[mi] = (wm*WROWS + mi*16 + fr)*32 + swz8;
    #pragma unroll
    for (int ni = 0; ni < 4; ++ni)  boff[ni] = BHO + (wn*64 + ni*16 + fr)*32 + swz8;

    f32x4 acc[MI][4] = {};

    // prologue: stage tile 0
    #pragma unroll
    for (int i = 0; i < PW; ++i) { gload16(gptr[i], &lds[loff[i]]); gptr[i] += 32; }
    VMCNT<0>(); BARRIER(); SB0();

    const int NT = K >> 5;
    int bb = 0;
    // -------- main loop: branchless body (single scheduling region) --------
    for (int t = 0; t < NT - 1; ++t) {
        const int nbuf = BUFS - bb;
        // staging for next tile (pinned early by VMEM SGB group below)
        #pragma unroll
        for (int i = 0; i < PW; ++i) { gload16(gptr[i], &lds[nbuf + loff[i]]); gptr[i] += 32; }
        // B-frags into registers (read once per step)
        f16x8 bh[4], bl[4];
        #pragma unroll
        for (int ni = 0; ni < 4; ++ni) {
            bh[ni] = *(const f16x8*)&lds[bb + boff[ni]];
            bl[ni] = *(const f16x8*)&lds[bb + 8192 + boff[ni]];
        }
        f16x8 ah = *(const f16x8*)&lds[bb + aoff[0]];
        f16x8 al = *(const f16x8*)&lds[bb + ALO + aoff[0]];
        SGB(0x010, PW, 0);   // PW x global_load_lds first (full-step slack for vmcnt)
        SGB(0x100, 10, 0);   // 8 B-reads + 2 A0-reads
        #pragma unroll
        for (int mi = 0; mi < MI; ++mi) {
            f16x8 ahn, aln;
            if (mi < MI - 1) {
                ahn = *(const f16x8*)&lds[bb + aoff[mi + 1]];
                aln = *(const f16x8*)&lds[bb + ALO + aoff[mi + 1]];
            }
            #pragma unroll
            for (int ni = 0; ni < 4; ++ni) {
                acc[mi][ni] = MFMA16(ah, bh[ni], acc[mi][ni], 0, 0, 0);
                acc[mi][ni] = MFMA16(ah, bl[ni], acc[mi][ni], 0, 0, 0);
                acc[mi][ni] = MFMA16(al, bh[ni], acc[mi][ni], 0, 0, 0);
            }
            if (mi < MI - 1) SGB(0x100, 2, 0);   // mi+1's A-reads issue under mi's MFMAs
            SGB(0x008, 12, 0);                   // then the 12 MFMAs of mi
            if (mi < MI - 1) { ah = ahn; al = aln; }
        }
        VMCNT<0>(); BARRIER(); SB0();
        bb = nbuf;
    }
    // -------- peeled last step: no staging --------
    {
        f16x8 bh[4], bl[4];
        #pragma unroll
        for (int ni = 0; ni < 4; ++ni) {
            bh[ni] = *(const f16x8*)&lds[bb + boff[ni]];
            bl[ni] = *(const f16x8*)&lds[bb + 8192 + boff[ni]];
        }
        f16x8 ah = *(const f16x8*)&lds[bb + aoff[0]];
        f16x8 al = *(const f16x8*)&lds[bb + ALO + aoff[0]];
        SGB(0x100, 10, 0);
        #pragma unroll
        for (int mi = 0; mi < MI; ++mi) {
            f16x8 ahn, aln;
            if (mi < MI - 1) {
                ahn = *(const f16x8*)&lds[bb + aoff[mi + 1]];
                aln = *(const f16x8*)&lds[bb + ALO + aoff[mi + 1]];
            }
            #pragma unroll
            for (int ni = 0; ni < 4; ++ni) {
                acc[mi][ni] = MFMA16(ah, bh[ni], acc[mi][ni], 0, 0, 0);
                acc[mi][ni] = MFMA16(ah, bl[ni], acc[mi][ni], 0, 0, 0);
                acc[mi][ni] = MFMA16(al, bh[ni], acc[mi][ni], 0, 0, 0);
            }
            if (mi < MI - 1) SGB(0x100, 2, 0);
            SGB(0x008, 12, 0);
            if (mi < MI - 1) { ah = ahn; al = aln; }
        }
    }

    // ---- epilogue: bias (+ReLU+split | f32 store) ----
    // 16x16 D mapping (HW-verified): n = lane&15, m = (lane>>4)*4 + reg
    #pragma unroll
    for (int ni = 0; ni < 4; ++ni) {
        const int n = n0 + wn*64 + ni*16 + fr;
        if (!SPLITOUT && n >= Nstore) continue;
        const float bv = bias[n];
        #pragma unroll
        for (int mi = 0; mi < MI; ++mi) {
            #pragma unroll
            for (int j = 0; j < 4; ++j) {
                const int m = m0 + wm*WROWS + mi*16 + fg*4 + j;
                float v = acc[mi][ni][j] + bv;
                if (SPLITOUT) {
                    v = fmaxf(v, 0.f);
                    const _Float16 hh = (_Float16)v;
                    Oh[(size_t)m * ldo + n] = hh;
                    Ol[(size_t)m * ldo + n] = (_Float16)(v - (float)hh);
                } else {
                    Of[(size_t)m * ldo + n] = v;
                }
            }
        }
    }
}

// ================= fallback path (R2, known-passing) =================
#define TILE_M 128
#define TILE_N 128
#define TILE_K 32
#define LDSK   40

template<bool RELU, bool NGUARD>
__global__ __launch_bounds__(256, 2)
void gemm_split3(const float* __restrict__ A, const float* __restrict__ B,
                 const float* __restrict__ bias, float* __restrict__ C,
                 int K, int ldc, int Nreal)
{
    __shared__ _Float16 Ah[TILE_M][LDSK];
    __shared__ _Float16 Al[TILE_M][LDSK];
    __shared__ _Float16 Bh[TILE_N][LDSK];
    __shared__ _Float16 Bl[TILE_N][LDSK];

    const int tid  = threadIdx.x;
    const int lane = tid & 63;
    const int wave = tid >> 6;
    const int wr   = wave >> 1;
    const int wc   = wave & 1;
    const int m0   = blockIdx.x * TILE_M;
    const int n0   = blockIdx.y * TILE_N;
    const int srow = tid >> 3;
    const int scol = (tid & 7) << 2;
    const int fr = lane & 15;
    const int fg = lane >> 4;

    f32x4 acc[4][4] = {};

    for (int kt = 0; kt < K; kt += TILE_K) {
        __syncthreads();
        #pragma unroll
        for (int p = 0; p < 4; ++p) {
            const int row = srow + p * 32;
            f32x4 v = *(const f32x4*)(A + (size_t)(m0 + row) * K + kt + scol);
            f16x4 hv, lv;
            split4(v, hv, lv);
            *(f16x4*)&Ah[row][scol] = hv;
            *(f16x4*)&Al[row][scol] = lv;
        }
        #pragma unroll
        for (int p = 0; p < 4; ++p) {
            const int row = srow + p * 32;
            f32x4 v = {0.f, 0.f, 0.f, 0.f};
            if (!NGUARD || (n0 + row) < Nreal)
                v = *(const f32x4*)(B + (size_t)(n0 + row) * K + kt + scol);
            f16x4 hv, lv;
            split4(v, hv, lv);
            *(f16x4*)&Bh[row][scol] = hv;
            *(f16x4*)&Bl[row][scol] = lv;
        }
        __syncthreads();

        f16x8 ah[4], al[4];
        #pragma unroll
        for (int mi = 0; mi < 4; ++mi) {
            const int r = wr * 64 + mi * 16 + fr;
            ah[mi] = *(const f16x8*)&Ah[r][fg * 8];
            al[mi] = *(const f16x8*)&Al[r][fg * 8];
        }
        #pragma unroll
        for (int ni = 0; ni < 4; ++ni) {
            const int r = wc * 64 + ni * 16 + fr;
            const f16x8 bh = *(const f16x8*)&Bh[r][fg * 8];
            const f16x8 bl = *(const f16x8*)&Bl[r][fg * 8];
            #pragma unroll
            for (int mi = 0; mi < 4; ++mi) {
                acc[mi][ni] = __builtin_amdgcn_mfma_f32_16x16x32_f16(ah[mi], bh, acc[mi][ni], 0, 0, 0);
                acc[mi][ni] = __builtin_amdgcn_mfma_f32_16x16x32_f16(ah[mi], bl, acc[mi][ni], 0, 0, 0);
                acc[mi][ni] = __builtin_amdgcn_mfma_f32_16x16x32_f16(al[mi], bh, acc[mi][ni], 0, 0, 0);
            }
        }
    }

    #pragma unroll
    for (int ni = 0; ni < 4; ++ni) {
        const int n = n0 + wc * 64 + ni * 16 + fr;
        if (NGUARD && n >= Nreal) continue;
        const float bv = bias[n];
        #pragma unroll
        for (int mi = 0; mi < 4; ++mi) {
            #pragma unroll
            for (int j = 0; j < 4; ++j) {
                const int m = m0 + wr * 64 + mi * 16 + fg * 4 + j;
                float val = acc[mi][ni][j] + bv;
                if (RELU) val = fmaxf(val, 0.f);
                C[(size_t)m * ldc + n] = val;
            }
        }
    }
}

// In-place row softmax: one wave per row (cols <= 1024).
__global__ __launch_bounds__(256)
void softmax_rows(float* __restrict__ out, int rows, int cols)
{
    const int lane = threadIdx.x & 63;
    const int row  = blockIdx.x * 4 + (threadIdx.x >> 6);
    if (row >= rows) return;
    float* p = out + (size_t)row * cols;

    float v[16];
    float mx = -3.4e38f;
    #pragma unroll
    for (int j = 0; j < 16; ++j) {
        const int c = lane + j * 64;
        v[j] = (c < cols) ? p[c] : -3.4e38f;
        mx = fmaxf(mx, v[j]);
    }
    #pragma unroll
    for (int off = 32; off > 0; off >>= 1)
        mx = fmaxf(mx, __shfl_xor(mx, off));

    float s = 0.f;
    #pragma unroll
    for (int j = 0; j < 16; ++j) {
        const int c = lane + j * 64;
        const float e = (c < cols) ? __expf(v[j] - mx) : 0.f;
        v[j] = e;
        s += e;
    }
    #pragma unroll
    for (int off = 32; off > 0; off >>= 1)
        s += __shfl_xor(s, off);

    const float inv = 1.f / s;
    #pragma unroll
    for (int j = 0; j < 16; ++j) {
        const int c = lane + j * 64;
        if (c < cols) p[c] = v[j] * inv;
    }
}

// ================= host =================
extern "C" void kernel_launch(void* const* d_in, const int* in_sizes, int n_in,
                              void* d_out, int out_size, void* d_ws, size_t ws_size,
                              hipStream_t stream)
{
    const float* x  = (const float*)d_in[0];   // [8192, 4096]
    const float* w1 = (const float*)d_in[1];   // [4096, 4096]
    const float* b1 = (const float*)d_in[2];   // [4096]
    const float* w2 = (const float*)d_in[3];   // [1000, 4096]
    const float* b2 = (const float*)d_in[4];   // [1000]
    float* out = (float*)d_out;                // [8192, 1000] fp32

    const size_t SZ_X  = (size_t)8192 * 4096 * 2;
    const size_t SZ_W1 = (size_t)4096 * 4096 * 2;
    const size_t SZ_W2 = (size_t)1024 * 4096 * 2;

    size_t off = 0;
    auto take = [&](size_t b) { size_t o = off; off += (b + 255) & ~(size_t)255; return o; };
    const size_t o_xh  = take(SZ_X),  o_xl  = take(SZ_X);
    const size_t o_w1h = take(SZ_W1), o_w1l = take(SZ_W1);
    const size_t o_w2h = take(SZ_W2), o_w2l = take(SZ_W2);
    const size_t o_ah  = take(SZ_X),  o_al  = take(SZ_X);
    const size_t need = off;

    bool attr_ok =
        (hipFuncSetAttribute((const void*)gemm3_v8<8, true, true>,
                             hipFuncAttributeMaxDynamicSharedMemorySize, 131072) == hipSuccess) &&
        (hipFuncSetAttribute((const void*)gemm3_v8<4, false, false>,
                             hipFuncAttributeMaxDynamicSharedMemorySize, 131072) == hipSuccess);

    const dim3 blk256(256, 1, 1), blk512(512, 1, 1);

    if (attr_ok && ws_size >= need) {
        char* w = (char*)d_ws;
        _Float16 *xh  = (_Float16*)(w + o_xh),  *xl  = (_Float16*)(w + o_xl);
        _Float16 *w1h = (_Float16*)(w + o_w1h), *w1l = (_Float16*)(w + o_w1l);
        _Float16 *w2h = (_Float16*)(w + o_w2h), *w2l = (_Float16*)(w + o_w2l);
        _Float16 *ath = (_Float16*)(w + o_ah),  *atl = (_Float16*)(w + o_al);

        hipLaunchKernelGGL(split_rows, dim3(2048), blk256, 0, stream, x,  xh,  xl,  8192, (long long)8192 * 1024);
        hipLaunchKernelGGL(split_rows, dim3(2048), blk256, 0, stream, w1, w1h, w1l, 4096, (long long)4096 * 1024);
        hipLaunchKernelGGL(split_rows, dim3(1024), blk256, 0, stream, w2, w2h, w2l, 1000, (long long)1024 * 1024);

        // GEMM1: act(hi/lo) = relu(x @ w1^T + b1)   M=8192 N=4096 K=4096, BM=256, chunked swizzle
        hipLaunchKernelGGL((gemm3_v8<8, true, true>), dim3(512), blk512, 131072, stream,
                           xh, xl, w1h, w1l, b1, ath, atl, (float*)nullptr, 4096, 4096, 4096, 16);
        // GEMM2: logits = act @ w2^T + b2           M=8192 N=1024(pad) K=4096, BM=128, bn-inner
        hipLaunchKernelGGL((gemm3_v8<4, false, false>), dim3(256), blk512, 98304, stream,
                           ath, atl, w2h, w2l, b2, (_Float16*)nullptr, (_Float16*)nullptr,
                           out, 1000, 1000, 4096, 4);
        hipLaunchKernelGGL(softmax_rows, dim3(2048), blk256, 0, stream, out, 8192, 1000);
    } else {
        float* act = (float*)d_ws;
        hipLaunchKernelGGL((gemm_split3<true, false>), dim3(64, 32), blk256, 0, stream,
                           x, w1, b1, act, 4096, 4096, 4096);
        hipLaunchKernelGGL((gemm_split3<false, true>), dim3(64, 8), blk256, 0, stream,
                           act, w2, b2, out, 4096, 1000, 1000);
        hipLaunchKernelGGL(softmax_rows, dim3(2048), blk256, 0, stream, out, 8192, 1000);
    }
}